// Round 4
// baseline (8609.794 us; speedup 1.0000x reference)
//
#include <hip/hip_runtime.h>
#include <hip/hip_bf16.h>

// Problem constants
#define BB 64
#define TT 512
#define DD 128
#define HH 256
#define G4 1024   // 4*H
#define CC 50

typedef __bf16 bf16x8 __attribute__((ext_vector_type(8)));
typedef float  f32x4  __attribute__((ext_vector_type(4)));
typedef float  f32x2  __attribute__((ext_vector_type(2)));

__device__ __forceinline__ float bl16(unsigned u) { return __uint_as_float(u << 16); }
__device__ __forceinline__ float bh16(unsigned u) { return __uint_as_float(u & 0xffff0000u); }

__device__ __forceinline__ float sigf(float x) {
    return 1.f / (1.f + __expf(-x));
}
__device__ __forceinline__ float tanh_s(float x) {
    float ax = fabsf(x);
    float e = __expf(-2.f * ax);         // (0,1], no overflow
    float r = (1.f - e) / (1.f + e);
    return copysignf(r, x);
}

// ---------------------------------------------------------------------------
// Kernel 0: f32 -> bf16 conversion (8 elements/thread)
// ---------------------------------------------------------------------------
__global__ __launch_bounds__(256) void k_cvt(
    const float* __restrict__ src, __hip_bfloat16* __restrict__ dst, int n)
{
    int i = (blockIdx.x * 256 + threadIdx.x) * 8;
    if (i + 8 <= n) {
        float4 a = *(const float4*)(src + i);
        float4 b = *(const float4*)(src + i + 4);
        __hip_bfloat16 o[8];
        o[0] = __float2bfloat16(a.x); o[1] = __float2bfloat16(a.y);
        o[2] = __float2bfloat16(a.z); o[3] = __float2bfloat16(a.w);
        o[4] = __float2bfloat16(b.x); o[5] = __float2bfloat16(b.y);
        o[6] = __float2bfloat16(b.z); o[7] = __float2bfloat16(b.w);
        *(uint4*)(dst + i) = *(const uint4*)o;
    }
}

// ---------------------------------------------------------------------------
// Kernel 1: xg[dir][bt][gate] = emb[words[bt]] @ W_ih[dir]^T + b[dir]  (bf16 out)
// grid: 2048 m_tiles * 32 n_groups = 65536 blocks, 256 threads (4 waves)
// ---------------------------------------------------------------------------
__global__ __launch_bounds__(256) void k_xg(
    const int* __restrict__ words,
    const __hip_bfloat16* __restrict__ emb,     // converted bf16 [50000][128]
    const __hip_bfloat16* __restrict__ Wf,      // converted bf16 [1024][128]
    const float* __restrict__ bfv,              // f32 [1024]
    const __hip_bfloat16* __restrict__ Wb,
    const float* __restrict__ bbv,
    __hip_bfloat16* __restrict__ xg)
{
    int blk = blockIdx.x;
    int m_tile = blk >> 5;
    int n_group = blk & 31;
    int wave = threadIdx.x >> 6;
    int lane = threadIdx.x & 63;
    int n_tile = n_group * 4 + wave;          // 0..127  (gate dim 2048 / 16)
    int n = lane & 15;
    int quad = lane >> 4;

    int gate_g = n_tile * 16 + n;             // 0..2047
    int dir = gate_g >> 10;
    int gate = gate_g & 1023;
    const __hip_bfloat16* W    = dir ? Wb : Wf;
    const float*          bias = dir ? bbv : bfv;

    int btrow_a = m_tile * 16 + n;            // A row held by this lane (m = lane&15)
    int word = words[btrow_a];
    const __hip_bfloat16* arow = emb + (size_t)word * DD + quad * 8;
    const __hip_bfloat16* brow = W + (size_t)gate * DD + quad * 8;

    f32x4 acc = {0.f, 0.f, 0.f, 0.f};
#pragma unroll
    for (int kf = 0; kf < 4; ++kf) {          // K = 128 = 4 * 32
        bf16x8 a = *(const bf16x8*)(arow + kf * 32);
        bf16x8 b = *(const bf16x8*)(brow + kf * 32);
        acc = __builtin_amdgcn_mfma_f32_16x16x32_bf16(a, b, acc, 0, 0, 0);
    }
    float bv = bias[gate];
    size_t dbase = (size_t)dir * (size_t)(BB * TT * G4);
#pragma unroll
    for (int r = 0; r < 4; ++r) {
        int row = m_tile * 16 + quad * 4 + r;  // C/D: row=(lane>>4)*4+reg, col=lane&15
        xg[dbase + (size_t)row * G4 + gate] = __float2bfloat16(acc[r] + bv);
    }
}

// ---------------------------------------------------------------------------
// Kernel 2: LSTM recurrence. One block per (b, dir), 1024 threads.
// Thread j owns gate row j. Half of W_hh row cached in VGPRs, half streamed.
// ---------------------------------------------------------------------------
__global__ __launch_bounds__(1024) void k_lstm(
    const __hip_bfloat16* __restrict__ xg,     // [2][B*T][1024]
    const __hip_bfloat16* __restrict__ Whh_f,  // converted bf16 [1024][256]
    const __hip_bfloat16* __restrict__ Whh_b,
    const int* __restrict__ seq_len,
    __hip_bfloat16* __restrict__ hcat)         // [B*T][512]  (fwd | bwd)
{
    int b = blockIdx.x & 63;
    int dir = blockIdx.x >> 6;
    int j = threadIdx.x;

    __shared__ __align__(16) float h_s[HH];
    __shared__ __align__(16) float c_s[HH];
    __shared__ float g_s[G4];

    if (j < HH) { h_s[j] = 0.f; c_s[j] = 0.f; }
    __syncthreads();

    const __hip_bfloat16* W = dir ? Whh_b : Whh_f;
    const uint4* wrow = (const uint4*)(W + (size_t)j * HH);  // 32 x uint4 (8 bf16 each)

    // cache first half of the row (k = 0..127) in registers: 16 uint4 = 64 VGPRs
    uint4 wreg[16];
#pragma unroll
    for (int kc = 0; kc < 16; ++kc) wreg[kc] = wrow[kc];

    int L = seq_len[b];
    const __hip_bfloat16* xgb = xg + (size_t)dir * (size_t)(BB * TT * G4)
                                   + (size_t)b * TT * G4;

    for (int t = 0; t < TT; ++t) {
        int tc = t;
        if (dir) tc = (t < L) ? (L - 1 - t) : t;

        f32x2 a2 = {0.f, 0.f};
#pragma unroll
        for (int kc = 0; kc < 16; ++kc) {      // registered half
            uint4 wv = wreg[kc];
            float4 h0 = *(const float4*)&h_s[kc * 8];
            float4 h1 = *(const float4*)&h_s[kc * 8 + 4];
            a2 += (f32x2){bl16(wv.x), bh16(wv.x)} * (f32x2){h0.x, h0.y};
            a2 += (f32x2){bl16(wv.y), bh16(wv.y)} * (f32x2){h0.z, h0.w};
            a2 += (f32x2){bl16(wv.z), bh16(wv.z)} * (f32x2){h1.x, h1.y};
            a2 += (f32x2){bl16(wv.w), bh16(wv.w)} * (f32x2){h1.z, h1.w};
        }
#pragma unroll 8
        for (int kc = 16; kc < 32; ++kc) {     // streamed half (L1/L2)
            uint4 wv = wrow[kc];
            float4 h0 = *(const float4*)&h_s[kc * 8];
            float4 h1 = *(const float4*)&h_s[kc * 8 + 4];
            a2 += (f32x2){bl16(wv.x), bh16(wv.x)} * (f32x2){h0.x, h0.y};
            a2 += (f32x2){bl16(wv.y), bh16(wv.y)} * (f32x2){h0.z, h0.w};
            a2 += (f32x2){bl16(wv.z), bh16(wv.z)} * (f32x2){h1.x, h1.y};
            a2 += (f32x2){bl16(wv.w), bh16(wv.w)} * (f32x2){h1.z, h1.w};
        }
        g_s[j] = a2.x + a2.y + __bfloat162float(xgb[(size_t)tc * G4 + j]);
        __syncthreads();

        if (j < HH) {
            float gi = g_s[j], gf = g_s[j + HH], gg = g_s[j + 2 * HH], go = g_s[j + 3 * HH];
            float i_ = sigf(gi), f_ = sigf(gf), G = tanh_s(gg), o_ = sigf(go);
            float cc = f_ * c_s[j] + i_ * G;
            c_s[j] = cc;
            float hh = o_ * tanh_s(cc);
            h_s[j] = hh;
            hcat[((size_t)(b * TT + tc)) * (2 * HH) + dir * HH + j] = __float2bfloat16(hh);
        }
        __syncthreads();
    }
}

// ---------------------------------------------------------------------------
// Kernel 3: feats = hcat @ fc_W^T + fc_b ; logits = log_softmax(feats)
// one wave per (b,t) row; 32768 blocks x 64 threads
// ---------------------------------------------------------------------------
__global__ __launch_bounds__(64) void k_fc(
    const __hip_bfloat16* __restrict__ hcat,  // [B*T][512]
    const __hip_bfloat16* __restrict__ fcW,   // converted bf16 [50][512]
    const float* __restrict__ fcb,            // f32 [50]
    float* __restrict__ logits)               // [B*T][50]
{
    int row = blockIdx.x;
    int tid = threadIdx.x;
    __shared__ __align__(16) float hrow[2 * HH];
    __shared__ float fbuf[CC + 2];

    {
        uint4 v = *(const uint4*)(hcat + (size_t)row * (2 * HH) + tid * 8);
        float* d = &hrow[tid * 8];
        d[0] = bl16(v.x); d[1] = bh16(v.x);
        d[2] = bl16(v.y); d[3] = bh16(v.y);
        d[4] = bl16(v.z); d[5] = bh16(v.z);
        d[6] = bl16(v.w); d[7] = bh16(v.w);
    }
    __syncthreads();

    if (tid < CC) {
        float acc = fcb[tid];
        const uint4* wr = (const uint4*)(fcW + (size_t)tid * (2 * HH));
#pragma unroll 8
        for (int kc = 0; kc < 64; ++kc) {
            uint4 wv = wr[kc];
            float4 h0 = *(const float4*)&hrow[kc * 8];
            float4 h1 = *(const float4*)&hrow[kc * 8 + 4];
            acc = fmaf(bl16(wv.x), h0.x, acc); acc = fmaf(bh16(wv.x), h0.y, acc);
            acc = fmaf(bl16(wv.y), h0.z, acc); acc = fmaf(bh16(wv.y), h0.w, acc);
            acc = fmaf(bl16(wv.z), h1.x, acc); acc = fmaf(bh16(wv.z), h1.y, acc);
            acc = fmaf(bl16(wv.w), h1.z, acc); acc = fmaf(bh16(wv.w), h1.w, acc);
        }
        fbuf[tid] = acc;
    }
    __syncthreads();

    float m = -1e30f;
    for (int i = 0; i < CC; ++i) m = fmaxf(m, fbuf[i]);
    float s = 0.f;
    for (int i = 0; i < CC; ++i) s += __expf(fbuf[i] - m);
    float lns = __logf(s);
    if (tid < CC) logits[(size_t)row * CC + tid] = fbuf[tid] - m - lns;
}

// ---------------------------------------------------------------------------
// Kernel 4: CRF forward scan + gold score; per-batch loss -> loss_b[b]
// 64 blocks (one per b) x 256 threads: q = tid>>6 splits i-dim 4 ways
// ---------------------------------------------------------------------------
__global__ __launch_bounds__(256) void k_crf(
    const float* __restrict__ logits,          // [B*T][50]
    const int* __restrict__ target,            // [B][T]
    const int* __restrict__ seq_len,
    const float* __restrict__ trans,           // f32 [50][50]
    const float* __restrict__ start_s,         // f32 [50]
    const float* __restrict__ end_s,           // f32 [50]
    float* __restrict__ loss_b)                // [64]
{
    const float L2E = 1.4426950408889634f;
    const float LN2 = 0.6931471805599453f;
    int b = blockIdx.x;
    int tid = threadIdx.x;
    int q = tid >> 6;
    int j = tid & 63;
    bool act = (j < CC);
    int L = seq_len[b];
    const float* lg = logits + (size_t)b * TT * CC;

    __shared__ float alpha2[64];
    __shared__ float mpart[4][64];
    __shared__ float spart[4][64];
    __shared__ float red[256];
    __shared__ float nbuf[CC + 2];

    int i0 = q * 13;
    int icnt = min(13, CC - i0);   // 13,13,13,11
    float treg[13];
    if (act) {
#pragma unroll
        for (int s = 0; s < 13; ++s)
            if (s < icnt) treg[s] = L2E * trans[(i0 + s) * CC + j];
    }
    if (q == 0 && act) alpha2[j] = L2E * (lg[j] + start_s[j]);
    __syncthreads();

    float v[13];
    for (int t = 1; t < L; ++t) {
        float mq = -1e30f;
        if (act) {
#pragma unroll
            for (int s = 0; s < 13; ++s)
                if (s < icnt) { v[s] = alpha2[i0 + s] + treg[s]; mq = fmaxf(mq, v[s]); }
        }
        mpart[q][j] = mq;
        __syncthreads();
        float M = fmaxf(fmaxf(mpart[0][j], mpart[1][j]), fmaxf(mpart[2][j], mpart[3][j]));
        float sq = 0.f;
        if (act) {
#pragma unroll
            for (int s = 0; s < 13; ++s)
                if (s < icnt) sq += exp2f(v[s] - M);
        }
        spart[q][j] = sq;
        __syncthreads();
        if (q == 0 && act) {
            float S = spart[0][j] + spart[1][j] + spart[2][j] + spart[3][j];
            alpha2[j] = M + log2f(S) + L2E * lg[(size_t)t * CC + j];
        }
        __syncthreads();
    }

    if (q == 0 && act) nbuf[j] = alpha2[j] + L2E * end_s[j];

    // gold partial sums (natural log domain)
    float gp = 0.f;
    const int* tg = target + b * TT;
    for (int t = tid; t < TT; t += 256) {
        if (t < L) {
            int c = tg[t];
            gp += lg[(size_t)t * CC + c];
            if (t >= 1) gp += trans[tg[t - 1] * CC + c];
        }
    }
    red[tid] = gp;
    __syncthreads();

    if (tid == 0) {
        float m2 = -1e30f;
        for (int i = 0; i < CC; ++i) m2 = fmaxf(m2, nbuf[i]);
        float s2 = 0.f;
        for (int i = 0; i < CC; ++i) s2 += exp2f(nbuf[i] - m2);
        float norm_nat = (m2 + log2f(s2)) * LN2;
        float g = 0.f;
        for (int i = 0; i < 256; ++i) g += red[i];
        g += start_s[tg[0]] + end_s[tg[L - 1]];
        loss_b[b] = norm_nat - g;              // plain store, no atomic
    }
}

// Final reduction of the 64 per-batch losses -> f32 scalar (reference dtype)
__global__ void k_fin(const float* __restrict__ loss_b, float* __restrict__ out)
{
    float s = 0.f;
    for (int i = 0; i < BB; ++i) s += loss_b[i];
    out[0] = s * (1.f / BB);
}

// ---------------------------------------------------------------------------
extern "C" void kernel_launch(void* const* d_in, const int* in_sizes, int n_in,
                              void* d_out, int out_size, void* d_ws, size_t ws_size,
                              hipStream_t stream)
{
    const int* words   = (const int*)d_in[0];
    const int* target  = (const int*)d_in[1];
    const int* seq_len = (const int*)d_in[2];
    const float* emb    = (const float*)d_in[3];
    const float* W_ih_f = (const float*)d_in[4];
    const float* W_hh_f = (const float*)d_in[5];
    const float* b_f    = (const float*)d_in[6];
    const float* W_ih_b = (const float*)d_in[7];
    const float* W_hh_b = (const float*)d_in[8];
    const float* b_b    = (const float*)d_in[9];
    const float* fc_W   = (const float*)d_in[10];
    const float* fc_b   = (const float*)d_in[11];
    const float* trans  = (const float*)d_in[12];
    const float* start_s= (const float*)d_in[13];
    const float* end_s  = (const float*)d_in[14];

    char* ws = (char*)d_ws;
    // workspace layout (bytes):
    //   xg     : 134217728                         @ 0
    //   hcat   :  33554432                         @ 134217728
    //   logits :   6553600                         @ 167772160
    //   loss_b :       256                         @ 174325760
    //   emb_bf :  12800000 (6,400,000 bf16)        @ 174326016
    //   wih_f  :    262144                         @ 187126016
    //   whh_f  :    524288                         @ 187388160
    //   wih_b  :    262144                         @ 187912448
    //   whh_b  :    524288                         @ 188174592
    //   fcw_bf :     51200                         @ 188698880   (end 188750080)
    __hip_bfloat16* xg     = (__hip_bfloat16*)ws;
    __hip_bfloat16* hcat   = (__hip_bfloat16*)(ws + 134217728);
    float*          logits = (float*)(ws + 167772160);
    float*          loss_b = (float*)(ws + 174325760);
    __hip_bfloat16* emb_bf = (__hip_bfloat16*)(ws + 174326016);
    __hip_bfloat16* wih_f  = (__hip_bfloat16*)(ws + 187126016);
    __hip_bfloat16* whh_f  = (__hip_bfloat16*)(ws + 187388160);
    __hip_bfloat16* wih_b  = (__hip_bfloat16*)(ws + 187912448);
    __hip_bfloat16* whh_b  = (__hip_bfloat16*)(ws + 188174592);
    __hip_bfloat16* fcw_bf = (__hip_bfloat16*)(ws + 188698880);

    // f32 -> bf16 weight conversions
    k_cvt<<<3125, 256, 0, stream>>>(emb,    emb_bf, 6400000);
    k_cvt<<<64,   256, 0, stream>>>(W_ih_f, wih_f,  131072);
    k_cvt<<<128,  256, 0, stream>>>(W_hh_f, whh_f,  262144);
    k_cvt<<<64,   256, 0, stream>>>(W_ih_b, wih_b,  131072);
    k_cvt<<<128,  256, 0, stream>>>(W_hh_b, whh_b,  262144);
    k_cvt<<<13,   256, 0, stream>>>(fc_W,   fcw_bf, 25600);

    k_xg  <<<65536, 256, 0, stream>>>(words, emb_bf, wih_f, b_f, wih_b, b_b, xg);
    k_lstm<<<128, 1024, 0, stream>>>(xg, whh_f, whh_b, seq_len, hcat);
    k_fc  <<<32768, 64, 0, stream>>>(hcat, fcw_bf, fc_b, logits);
    k_crf <<<64, 256, 0, stream>>>(logits, target, seq_len, trans, start_s, end_s, loss_b);
    k_fin <<<1, 1, 0, stream>>>(loss_b, (float*)d_out);
}

// Round 5
// 2436.617 us; speedup vs baseline: 3.5335x; 3.5335x over previous
//
#include <hip/hip_runtime.h>
#include <hip/hip_bf16.h>

// Problem constants
#define BB 64
#define TT 512
#define DD 128
#define HH 256
#define G4 1024   // 4*H
#define CC 50

typedef __bf16 bf16x8 __attribute__((ext_vector_type(8)));
typedef __bf16 bf16x2 __attribute__((ext_vector_type(2)));
typedef float  f32x4  __attribute__((ext_vector_type(4)));
typedef float  f32x2  __attribute__((ext_vector_type(2)));

#if defined(__has_builtin)
#if __has_builtin(__builtin_amdgcn_fdot2_f32_bf16)
#define HAS_DOT2 1
#endif
#endif

__device__ __forceinline__ float bl16(unsigned u) { return __uint_as_float(u << 16); }
__device__ __forceinline__ float bh16(unsigned u) { return __uint_as_float(u & 0xffff0000u); }

__device__ __forceinline__ float sigf(float x) {
    return 1.f / (1.f + __expf(-x));
}
__device__ __forceinline__ float tanh_s(float x) {
    float ax = fabsf(x);
    float e = __expf(-2.f * ax);         // (0,1], no overflow
    float r = (1.f - e) / (1.f + e);
    return copysignf(r, x);
}

#ifdef HAS_DOT2
__device__ __forceinline__ float row4(float acc, uint4 w, uint4 h) {
    acc = __builtin_amdgcn_fdot2_f32_bf16(__builtin_bit_cast(bf16x2, w.x),
                                          __builtin_bit_cast(bf16x2, h.x), acc, false);
    acc = __builtin_amdgcn_fdot2_f32_bf16(__builtin_bit_cast(bf16x2, w.y),
                                          __builtin_bit_cast(bf16x2, h.y), acc, false);
    acc = __builtin_amdgcn_fdot2_f32_bf16(__builtin_bit_cast(bf16x2, w.z),
                                          __builtin_bit_cast(bf16x2, h.z), acc, false);
    acc = __builtin_amdgcn_fdot2_f32_bf16(__builtin_bit_cast(bf16x2, w.w),
                                          __builtin_bit_cast(bf16x2, h.w), acc, false);
    return acc;
}
#else
__device__ __forceinline__ f32x2 row4f(f32x2 acc, uint4 w, float4 h0, float4 h1) {
    acc += (f32x2){bl16(w.x), bh16(w.x)} * (f32x2){h0.x, h0.y};
    acc += (f32x2){bl16(w.y), bh16(w.y)} * (f32x2){h0.z, h0.w};
    acc += (f32x2){bl16(w.z), bh16(w.z)} * (f32x2){h1.x, h1.y};
    acc += (f32x2){bl16(w.w), bh16(w.w)} * (f32x2){h1.z, h1.w};
    return acc;
}
#endif

// ---------------------------------------------------------------------------
// Kernel 0: f32 -> bf16 conversion (8 elements/thread)
// ---------------------------------------------------------------------------
__global__ __launch_bounds__(256) void k_cvt(
    const float* __restrict__ src, __hip_bfloat16* __restrict__ dst, int n)
{
    int i = (blockIdx.x * 256 + threadIdx.x) * 8;
    if (i + 8 <= n) {
        float4 a = *(const float4*)(src + i);
        float4 b = *(const float4*)(src + i + 4);
        __hip_bfloat16 o[8];
        o[0] = __float2bfloat16(a.x); o[1] = __float2bfloat16(a.y);
        o[2] = __float2bfloat16(a.z); o[3] = __float2bfloat16(a.w);
        o[4] = __float2bfloat16(b.x); o[5] = __float2bfloat16(b.y);
        o[6] = __float2bfloat16(b.z); o[7] = __float2bfloat16(b.w);
        *(uint4*)(dst + i) = *(const uint4*)o;
    }
}

// ---------------------------------------------------------------------------
// Kernel 0b: pack W_hh (f32 [1024][256]) into lane-coalesced bf16 chunks.
// Thread j owns gate rows {j, 256+j, 512+j, 768+j} in k_lstm.
// Wreg[((dir*3+rs)*32+kc)*256 + j] = 8 bf16 of row rs*256+j, k in [8kc,8kc+8)
// Wo  [((dir*32)+kc)*256 + j]      = same for row 768+j (the o gate)
// grid: 2 dir * 4 rs * 32 kc = 256 blocks x 256 threads
// ---------------------------------------------------------------------------
__global__ __launch_bounds__(256) void k_pack(
    const float* __restrict__ Wf, const float* __restrict__ Wb,
    uint4* __restrict__ Wreg, uint4* __restrict__ Wo)
{
    int blk = blockIdx.x;
    int kc = blk & 31;
    int rs = (blk >> 5) & 3;
    int dir = blk >> 7;
    int j = threadIdx.x;
    const float* src = (dir ? Wb : Wf) + ((size_t)(rs * 256 + j)) * 256 + kc * 8;
    float4 a = *(const float4*)src;
    float4 b = *(const float4*)(src + 4);
    __hip_bfloat16 o[8];
    o[0] = __float2bfloat16(a.x); o[1] = __float2bfloat16(a.y);
    o[2] = __float2bfloat16(a.z); o[3] = __float2bfloat16(a.w);
    o[4] = __float2bfloat16(b.x); o[5] = __float2bfloat16(b.y);
    o[6] = __float2bfloat16(b.z); o[7] = __float2bfloat16(b.w);
    uint4 v = *(const uint4*)o;
    if (rs < 3) Wreg[(((dir * 3 + rs) * 32 + kc) * 256) + j] = v;
    else        Wo[((dir * 32 + kc) * 256) + j] = v;
}

// ---------------------------------------------------------------------------
// Kernel 1: xg[dir][bt][gate] = emb[words[bt]] @ W_ih[dir]^T + b[dir]  (bf16 out)
// ---------------------------------------------------------------------------
__global__ __launch_bounds__(256) void k_xg(
    const int* __restrict__ words,
    const __hip_bfloat16* __restrict__ emb,
    const __hip_bfloat16* __restrict__ Wf, const float* __restrict__ bfv,
    const __hip_bfloat16* __restrict__ Wb, const float* __restrict__ bbv,
    __hip_bfloat16* __restrict__ xg)
{
    int blk = blockIdx.x;
    int m_tile = blk >> 5;
    int n_group = blk & 31;
    int wave = threadIdx.x >> 6;
    int lane = threadIdx.x & 63;
    int n_tile = n_group * 4 + wave;
    int n = lane & 15;
    int quad = lane >> 4;

    int gate_g = n_tile * 16 + n;
    int dir = gate_g >> 10;
    int gate = gate_g & 1023;
    const __hip_bfloat16* W    = dir ? Wb : Wf;
    const float*          bias = dir ? bbv : bfv;

    int btrow_a = m_tile * 16 + n;
    int word = words[btrow_a];
    const __hip_bfloat16* arow = emb + (size_t)word * DD + quad * 8;
    const __hip_bfloat16* brow = W + (size_t)gate * DD + quad * 8;

    f32x4 acc = {0.f, 0.f, 0.f, 0.f};
#pragma unroll
    for (int kf = 0; kf < 4; ++kf) {
        bf16x8 a = *(const bf16x8*)(arow + kf * 32);
        bf16x8 b = *(const bf16x8*)(brow + kf * 32);
        acc = __builtin_amdgcn_mfma_f32_16x16x32_bf16(a, b, acc, 0, 0, 0);
    }
    float bv = bias[gate];
    size_t dbase = (size_t)dir * (size_t)(BB * TT * G4);
#pragma unroll
    for (int r = 0; r < 4; ++r) {
        int row = m_tile * 16 + quad * 4 + r;
        xg[dbase + (size_t)row * G4 + gate] = __float2bfloat16(acc[r] + bv);
    }
}

// ---------------------------------------------------------------------------
// Kernel 2: LSTM recurrence v2. One block per (b,dir), 256 threads (4 waves,
// 1 wave/SIMD). Thread j owns cell j: gate rows i,f,g in 96 uint4 of VGPRs,
// row o: 14 chunks in LDS + 18 chunks streamed coalesced from packed L2-
// resident layout. h ping-pong in LDS (f32 + bf16), c in a register.
// One barrier per step; xg software-prefetched.
// ---------------------------------------------------------------------------
__global__ __launch_bounds__(256, 1) void k_lstm(
    const __hip_bfloat16* __restrict__ xg,     // [2][B*T][1024]
    const uint4* __restrict__ Wreg,            // packed rows i,f,g
    const uint4* __restrict__ Wo_g,            // packed row o
    const int* __restrict__ seq_len,
    __hip_bfloat16* __restrict__ hcat)         // [B*T][512]
{
    int b = blockIdx.x & 63;
    int dir = blockIdx.x >> 6;
    int j = threadIdx.x;

    __shared__ __align__(16) uint4 o_lds[14 * 256];          // 56 KB
    __shared__ __align__(16) float hf[2][HH];                // 2 KB
    __shared__ __align__(16) __hip_bfloat16 hb[2][HH];       // 1 KB

    // --- load resident weights ---
    const uint4* Wr = Wreg + (size_t)(dir * 3) * 32 * 256;
    uint4 w0[32], w1[32], w2[32];
#pragma unroll
    for (int kc = 0; kc < 32; ++kc) w0[kc] = Wr[(0 * 32 + kc) * 256 + j];
#pragma unroll
    for (int kc = 0; kc < 32; ++kc) w1[kc] = Wr[(1 * 32 + kc) * 256 + j];
#pragma unroll
    for (int kc = 0; kc < 32; ++kc) w2[kc] = Wr[(2 * 32 + kc) * 256 + j];
    const uint4* Wo = Wo_g + (size_t)dir * 32 * 256;
#pragma unroll
    for (int kc = 0; kc < 14; ++kc) o_lds[kc * 256 + j] = Wo[kc * 256 + j];

    hf[0][j] = 0.f;
    hb[0][j] = __float2bfloat16(0.f);
    float c = 0.f;
    int L = seq_len[b];
    const __hip_bfloat16* xgb = xg + (size_t)dir * (size_t)(BB * TT * G4)
                                   + (size_t)b * TT * G4;

    // prefetch xg for t=0
    int tc = dir ? (L - 1) : 0;
    float xv0 = __bfloat162float(xgb[(size_t)tc * G4 + j]);
    float xv1 = __bfloat162float(xgb[(size_t)tc * G4 + 256 + j]);
    float xv2 = __bfloat162float(xgb[(size_t)tc * G4 + 512 + j]);
    float xv3 = __bfloat162float(xgb[(size_t)tc * G4 + 768 + j]);
    __syncthreads();

    for (int t = 0; t < TT; ++t) {
        int cur = t & 1, nxt = cur ^ 1;

        // prefetch next xg row
        int tn = t + 1;
        int tcn = dir ? ((tn < L) ? (L - 1 - tn) : tn) : tn;
        __hip_bfloat16 p0, p1, p2, p3;
        bool pf = (tn < TT);
        if (pf) {
            p0 = xgb[(size_t)tcn * G4 + j];
            p1 = xgb[(size_t)tcn * G4 + 256 + j];
            p2 = xgb[(size_t)tcn * G4 + 512 + j];
            p3 = xgb[(size_t)tcn * G4 + 768 + j];
        }

        // stream group A of row o (kc 14..22)
        uint4 oa[9];
#pragma unroll
        for (int i = 0; i < 9; ++i) oa[i] = Wo[(14 + i) * 256 + j];

#ifdef HAS_DOT2
        float a0 = 0.f, a1 = 0.f, a2 = 0.f, a3 = 0.f;
#pragma unroll
        for (int kc = 0; kc < 14; ++kc) {
            uint4 hv = *(const uint4*)&hb[cur][kc * 8];
            a0 = row4(a0, w0[kc], hv);
            a1 = row4(a1, w1[kc], hv);
            a2 = row4(a2, w2[kc], hv);
            a3 = row4(a3, o_lds[kc * 256 + j], hv);
        }
#pragma unroll
        for (int kc = 14; kc < 23; ++kc) {
            uint4 hv = *(const uint4*)&hb[cur][kc * 8];
            a0 = row4(a0, w0[kc], hv);
            a1 = row4(a1, w1[kc], hv);
            a2 = row4(a2, w2[kc], hv);
            a3 = row4(a3, oa[kc - 14], hv);
        }
        uint4 ob[9];
#pragma unroll
        for (int i = 0; i < 9; ++i) ob[i] = Wo[(23 + i) * 256 + j];
#pragma unroll
        for (int kc = 23; kc < 32; ++kc) {
            uint4 hv = *(const uint4*)&hb[cur][kc * 8];
            a0 = row4(a0, w0[kc], hv);
            a1 = row4(a1, w1[kc], hv);
            a2 = row4(a2, w2[kc], hv);
            a3 = row4(a3, ob[kc - 23], hv);
        }
        float gi = a0 + xv0, gf = a1 + xv1, gg = a2 + xv2, go = a3 + xv3;
#else
        f32x2 b0 = {0.f, 0.f}, b1 = {0.f, 0.f}, b2 = {0.f, 0.f}, b3 = {0.f, 0.f};
#pragma unroll
        for (int kc = 0; kc < 14; ++kc) {
            float4 h0 = *(const float4*)&hf[cur][kc * 8];
            float4 h1 = *(const float4*)&hf[cur][kc * 8 + 4];
            b0 = row4f(b0, w0[kc], h0, h1);
            b1 = row4f(b1, w1[kc], h0, h1);
            b2 = row4f(b2, w2[kc], h0, h1);
            b3 = row4f(b3, o_lds[kc * 256 + j], h0, h1);
        }
#pragma unroll
        for (int kc = 14; kc < 23; ++kc) {
            float4 h0 = *(const float4*)&hf[cur][kc * 8];
            float4 h1 = *(const float4*)&hf[cur][kc * 8 + 4];
            b0 = row4f(b0, w0[kc], h0, h1);
            b1 = row4f(b1, w1[kc], h0, h1);
            b2 = row4f(b2, w2[kc], h0, h1);
            b3 = row4f(b3, oa[kc - 14], h0, h1);
        }
        uint4 ob[9];
#pragma unroll
        for (int i = 0; i < 9; ++i) ob[i] = Wo[(23 + i) * 256 + j];
#pragma unroll
        for (int kc = 23; kc < 32; ++kc) {
            float4 h0 = *(const float4*)&hf[cur][kc * 8];
            float4 h1 = *(const float4*)&hf[cur][kc * 8 + 4];
            b0 = row4f(b0, w0[kc], h0, h1);
            b1 = row4f(b1, w1[kc], h0, h1);
            b2 = row4f(b2, w2[kc], h0, h1);
            b3 = row4f(b3, ob[kc - 23], h0, h1);
        }
        float gi = b0.x + b0.y + xv0, gf = b1.x + b1.y + xv1;
        float gg = b2.x + b2.y + xv2, go = b3.x + b3.y + xv3;
#endif
        float i_ = sigf(gi), f_ = sigf(gf), G = tanh_s(gg), o_ = sigf(go);
        c = f_ * c + i_ * G;
        float h = o_ * tanh_s(c);
        hf[nxt][j] = h;
        __hip_bfloat16 hbv = __float2bfloat16(h);
        hb[nxt][j] = hbv;
        hcat[((size_t)(b * TT + tc)) * (2 * HH) + dir * HH + j] = hbv;

        if (pf) {
            xv0 = __bfloat162float(p0); xv1 = __bfloat162float(p1);
            xv2 = __bfloat162float(p2); xv3 = __bfloat162float(p3);
        }
        tc = tcn;
        __syncthreads();
    }
}

// ---------------------------------------------------------------------------
// Kernel 3: feats = hcat @ fc_W^T + fc_b ; logits = log_softmax(feats)
// ---------------------------------------------------------------------------
__global__ __launch_bounds__(64) void k_fc(
    const __hip_bfloat16* __restrict__ hcat,
    const __hip_bfloat16* __restrict__ fcW,
    const float* __restrict__ fcb,
    float* __restrict__ logits)
{
    int row = blockIdx.x;
    int tid = threadIdx.x;
    __shared__ __align__(16) float hrow[2 * HH];
    __shared__ float fbuf[CC + 2];

    {
        uint4 v = *(const uint4*)(hcat + (size_t)row * (2 * HH) + tid * 8);
        float* d = &hrow[tid * 8];
        d[0] = bl16(v.x); d[1] = bh16(v.x);
        d[2] = bl16(v.y); d[3] = bh16(v.y);
        d[4] = bl16(v.z); d[5] = bh16(v.z);
        d[6] = bl16(v.w); d[7] = bh16(v.w);
    }
    __syncthreads();

    if (tid < CC) {
        float acc = fcb[tid];
        const uint4* wr = (const uint4*)(fcW + (size_t)tid * (2 * HH));
#pragma unroll 8
        for (int kc = 0; kc < 64; ++kc) {
            uint4 wv = wr[kc];
            float4 h0 = *(const float4*)&hrow[kc * 8];
            float4 h1 = *(const float4*)&hrow[kc * 8 + 4];
            acc = fmaf(bl16(wv.x), h0.x, acc); acc = fmaf(bh16(wv.x), h0.y, acc);
            acc = fmaf(bl16(wv.y), h0.z, acc); acc = fmaf(bh16(wv.y), h0.w, acc);
            acc = fmaf(bl16(wv.z), h1.x, acc); acc = fmaf(bh16(wv.z), h1.y, acc);
            acc = fmaf(bl16(wv.w), h1.z, acc); acc = fmaf(bh16(wv.w), h1.w, acc);
        }
        fbuf[tid] = acc;
    }
    __syncthreads();

    float m = -1e30f;
    for (int i = 0; i < CC; ++i) m = fmaxf(m, fbuf[i]);
    float s = 0.f;
    for (int i = 0; i < CC; ++i) s += __expf(fbuf[i] - m);
    float lns = __logf(s);
    if (tid < CC) logits[(size_t)row * CC + tid] = fbuf[tid] - m - lns;
}

// ---------------------------------------------------------------------------
// Kernel 4: CRF forward scan + gold score; per-batch loss -> loss_b[b]
// ---------------------------------------------------------------------------
__global__ __launch_bounds__(256) void k_crf(
    const float* __restrict__ logits,
    const int* __restrict__ target,
    const int* __restrict__ seq_len,
    const float* __restrict__ trans,
    const float* __restrict__ start_s,
    const float* __restrict__ end_s,
    float* __restrict__ loss_b)
{
    const float L2E = 1.4426950408889634f;
    const float LN2 = 0.6931471805599453f;
    int b = blockIdx.x;
    int tid = threadIdx.x;
    int q = tid >> 6;
    int j = tid & 63;
    bool act = (j < CC);
    int L = seq_len[b];
    const float* lg = logits + (size_t)b * TT * CC;

    __shared__ float alpha2[64];
    __shared__ float mpart[4][64];
    __shared__ float spart[4][64];
    __shared__ float red[256];
    __shared__ float nbuf[CC + 2];

    int i0 = q * 13;
    int icnt = min(13, CC - i0);
    float treg[13];
    if (act) {
#pragma unroll
        for (int s = 0; s < 13; ++s)
            if (s < icnt) treg[s] = L2E * trans[(i0 + s) * CC + j];
    }
    if (q == 0 && act) alpha2[j] = L2E * (lg[j] + start_s[j]);
    __syncthreads();

    float v[13];
    for (int t = 1; t < L; ++t) {
        float mq = -1e30f;
        if (act) {
#pragma unroll
            for (int s = 0; s < 13; ++s)
                if (s < icnt) { v[s] = alpha2[i0 + s] + treg[s]; mq = fmaxf(mq, v[s]); }
        }
        mpart[q][j] = mq;
        __syncthreads();
        float M = fmaxf(fmaxf(mpart[0][j], mpart[1][j]), fmaxf(mpart[2][j], mpart[3][j]));
        float sq = 0.f;
        if (act) {
#pragma unroll
            for (int s = 0; s < 13; ++s)
                if (s < icnt) sq += exp2f(v[s] - M);
        }
        spart[q][j] = sq;
        __syncthreads();
        if (q == 0 && act) {
            float S = spart[0][j] + spart[1][j] + spart[2][j] + spart[3][j];
            alpha2[j] = M + log2f(S) + L2E * lg[(size_t)t * CC + j];
        }
        __syncthreads();
    }

    if (q == 0 && act) nbuf[j] = alpha2[j] + L2E * end_s[j];

    float gp = 0.f;
    const int* tg = target + b * TT;
    for (int t = tid; t < TT; t += 256) {
        if (t < L) {
            int c = tg[t];
            gp += lg[(size_t)t * CC + c];
            if (t >= 1) gp += trans[tg[t - 1] * CC + c];
        }
    }
    red[tid] = gp;
    __syncthreads();

    if (tid == 0) {
        float m2 = -1e30f;
        for (int i = 0; i < CC; ++i) m2 = fmaxf(m2, nbuf[i]);
        float s2 = 0.f;
        for (int i = 0; i < CC; ++i) s2 += exp2f(nbuf[i] - m2);
        float norm_nat = (m2 + log2f(s2)) * LN2;
        float g = 0.f;
        for (int i = 0; i < 256; ++i) g += red[i];
        g += start_s[tg[0]] + end_s[tg[L - 1]];
        loss_b[b] = norm_nat - g;
    }
}

__global__ void k_fin(const float* __restrict__ loss_b, float* __restrict__ out)
{
    float s = 0.f;
    for (int i = 0; i < BB; ++i) s += loss_b[i];
    out[0] = s * (1.f / BB);
}

// ---------------------------------------------------------------------------
extern "C" void kernel_launch(void* const* d_in, const int* in_sizes, int n_in,
                              void* d_out, int out_size, void* d_ws, size_t ws_size,
                              hipStream_t stream)
{
    const int* words   = (const int*)d_in[0];
    const int* target  = (const int*)d_in[1];
    const int* seq_len = (const int*)d_in[2];
    const float* emb    = (const float*)d_in[3];
    const float* W_ih_f = (const float*)d_in[4];
    const float* W_hh_f = (const float*)d_in[5];
    const float* b_f    = (const float*)d_in[6];
    const float* W_ih_b = (const float*)d_in[7];
    const float* W_hh_b = (const float*)d_in[8];
    const float* b_b    = (const float*)d_in[9];
    const float* fc_W   = (const float*)d_in[10];
    const float* fc_b   = (const float*)d_in[11];
    const float* trans  = (const float*)d_in[12];
    const float* start_s= (const float*)d_in[13];
    const float* end_s  = (const float*)d_in[14];

    char* ws = (char*)d_ws;
    // workspace layout (bytes):
    //   xg     : 134217728                         @ 0
    //   hcat   :  33554432                         @ 134217728
    //   logits :   6553600                         @ 167772160
    //     (Wp_reg 786432 + Wp_o 262144 overlap the logits region: they are
    //      consumed by k_lstm BEFORE k_fc writes logits)
    //   loss_b :       256                         @ 174325760
    //   emb_bf :  12800000                         @ 174326016
    //   wih_f  :    262144                         @ 187126016
    //   wih_b  :    262144                         @ 187912448
    //   fcw_bf :     51200                         @ 188698880
    __hip_bfloat16* xg     = (__hip_bfloat16*)ws;
    __hip_bfloat16* hcat   = (__hip_bfloat16*)(ws + 134217728);
    float*          logits = (float*)(ws + 167772160);
    uint4*          Wp_reg = (uint4*)(ws + 167772160);
    uint4*          Wp_o   = (uint4*)(ws + 167772160 + 786432);
    float*          loss_b = (float*)(ws + 174325760);
    __hip_bfloat16* emb_bf = (__hip_bfloat16*)(ws + 174326016);
    __hip_bfloat16* wih_f  = (__hip_bfloat16*)(ws + 187126016);
    __hip_bfloat16* wih_b  = (__hip_bfloat16*)(ws + 187912448);
    __hip_bfloat16* fcw_bf = (__hip_bfloat16*)(ws + 188698880);

    k_cvt<<<3125, 256, 0, stream>>>(emb,    emb_bf, 6400000);
    k_cvt<<<64,   256, 0, stream>>>(W_ih_f, wih_f,  131072);
    k_cvt<<<64,   256, 0, stream>>>(W_ih_b, wih_b,  131072);
    k_cvt<<<13,   256, 0, stream>>>(fc_W,   fcw_bf, 25600);
    k_pack<<<256, 256, 0, stream>>>(W_hh_f, W_hh_b, Wp_reg, Wp_o);

    k_xg  <<<65536, 256, 0, stream>>>(words, emb_bf, wih_f, b_f, wih_b, b_b, xg);
    k_lstm<<<128, 256, 0, stream>>>(xg, Wp_reg, Wp_o, seq_len, hcat);
    k_fc  <<<32768, 64, 0, stream>>>(hcat, fcw_bf, fc_b, logits);
    k_crf <<<64, 256, 0, stream>>>(logits, target, seq_len, trans, start_s, end_s, loss_b);
    k_fin <<<1, 1, 0, stream>>>(loss_b, (float*)d_out);
}

// Round 6
// 2072.262 us; speedup vs baseline: 4.1548x; 1.1758x over previous
//
#include <hip/hip_runtime.h>
#include <hip/hip_bf16.h>

// Problem constants
#define BB 64
#define TT 512
#define DD 128
#define HH 256
#define G4 1024   // 4*H
#define CC 50

typedef __bf16 bf16x8 __attribute__((ext_vector_type(8)));
typedef float  f32x4  __attribute__((ext_vector_type(4)));
typedef _Float16 h16x2 __attribute__((ext_vector_type(2)));

#if defined(__has_builtin)
#if __has_builtin(__builtin_amdgcn_fdot2)
#define HAS_FDOT2 1
#endif
#endif

__device__ __forceinline__ float bl16(unsigned u) { return __uint_as_float(u << 16); }
__device__ __forceinline__ float bh16(unsigned u) { return __uint_as_float(u & 0xffff0000u); }

__device__ __forceinline__ float sigf(float x) {
    return 1.f / (1.f + __expf(-x));
}
__device__ __forceinline__ float tanh_s(float x) {
    float ax = fabsf(x);
    float e = __expf(-2.f * ax);
    float r = (1.f - e) / (1.f + e);
    return copysignf(r, x);
}

// 8-element f16 dot product chunk, f32 accumulate
__device__ __forceinline__ float dot8(float acc, uint4 w, uint4 h) {
#ifdef HAS_FDOT2
    acc = __builtin_amdgcn_fdot2(__builtin_bit_cast(h16x2, w.x),
                                 __builtin_bit_cast(h16x2, h.x), acc, false);
    acc = __builtin_amdgcn_fdot2(__builtin_bit_cast(h16x2, w.y),
                                 __builtin_bit_cast(h16x2, h.y), acc, false);
    acc = __builtin_amdgcn_fdot2(__builtin_bit_cast(h16x2, w.z),
                                 __builtin_bit_cast(h16x2, h.z), acc, false);
    acc = __builtin_amdgcn_fdot2(__builtin_bit_cast(h16x2, w.w),
                                 __builtin_bit_cast(h16x2, h.w), acc, false);
#else
    {
        h16x2 a = __builtin_bit_cast(h16x2, w.x), b = __builtin_bit_cast(h16x2, h.x);
        acc = fmaf((float)a.x, (float)b.x, acc); acc = fmaf((float)a.y, (float)b.y, acc);
        a = __builtin_bit_cast(h16x2, w.y); b = __builtin_bit_cast(h16x2, h.y);
        acc = fmaf((float)a.x, (float)b.x, acc); acc = fmaf((float)a.y, (float)b.y, acc);
        a = __builtin_bit_cast(h16x2, w.z); b = __builtin_bit_cast(h16x2, h.z);
        acc = fmaf((float)a.x, (float)b.x, acc); acc = fmaf((float)a.y, (float)b.y, acc);
        a = __builtin_bit_cast(h16x2, w.w); b = __builtin_bit_cast(h16x2, h.w);
        acc = fmaf((float)a.x, (float)b.x, acc); acc = fmaf((float)a.y, (float)b.y, acc);
    }
#endif
    return acc;
}

// ---------------------------------------------------------------------------
// Kernel 0: f32 -> bf16 conversion (8 elements/thread)
// ---------------------------------------------------------------------------
__global__ __launch_bounds__(256) void k_cvt(
    const float* __restrict__ src, __hip_bfloat16* __restrict__ dst, int n)
{
    int i = (blockIdx.x * 256 + threadIdx.x) * 8;
    if (i + 8 <= n) {
        float4 a = *(const float4*)(src + i);
        float4 b = *(const float4*)(src + i + 4);
        __hip_bfloat16 o[8];
        o[0] = __float2bfloat16(a.x); o[1] = __float2bfloat16(a.y);
        o[2] = __float2bfloat16(a.z); o[3] = __float2bfloat16(a.w);
        o[4] = __float2bfloat16(b.x); o[5] = __float2bfloat16(b.y);
        o[6] = __float2bfloat16(b.z); o[7] = __float2bfloat16(b.w);
        *(uint4*)(dst + i) = *(const uint4*)o;
    }
}

// ---------------------------------------------------------------------------
// Kernel 0b: pack W_hh (f32 [1024][256]) -> f16 lane-coalesced chunks.
// k_lstm thread j (of 512) owns rows {j, 512+j}.
// Wp[dir*64 + kc*2 + half][j] = 8 f16 of row (half*512 + j), k in [8kc, 8kc+8)
// grid: 2 dir * 32 kc * 2 half = 128 blocks x 512 threads
// ---------------------------------------------------------------------------
__global__ __launch_bounds__(512) void k_pack(
    const float* __restrict__ Wf, const float* __restrict__ Wb,
    uint4* __restrict__ Wp)
{
    int blk = blockIdx.x;
    int half = blk & 1;
    int kc = (blk >> 1) & 31;
    int dir = blk >> 6;
    int j = threadIdx.x;
    int row = half * 512 + j;
    const float* src = (dir ? Wb : Wf) + (size_t)row * 256 + kc * 8;
    float4 a = *(const float4*)src;
    float4 b = *(const float4*)(src + 4);
    _Float16 o[8];
    o[0] = (_Float16)a.x; o[1] = (_Float16)a.y;
    o[2] = (_Float16)a.z; o[3] = (_Float16)a.w;
    o[4] = (_Float16)b.x; o[5] = (_Float16)b.y;
    o[6] = (_Float16)b.z; o[7] = (_Float16)b.w;
    Wp[((size_t)dir * 64 + kc * 2 + half) * 512 + j] = *(const uint4*)o;
}

// ---------------------------------------------------------------------------
// Kernel 1: xg[dir][bt][gate] = emb[words[bt]] @ W_ih[dir]^T + b[dir]  (bf16)
// ---------------------------------------------------------------------------
__global__ __launch_bounds__(256) void k_xg(
    const int* __restrict__ words,
    const __hip_bfloat16* __restrict__ emb,
    const __hip_bfloat16* __restrict__ Wf, const float* __restrict__ bfv,
    const __hip_bfloat16* __restrict__ Wb, const float* __restrict__ bbv,
    __hip_bfloat16* __restrict__ xg)
{
    int blk = blockIdx.x;
    int m_tile = blk >> 5;
    int n_group = blk & 31;
    int wave = threadIdx.x >> 6;
    int lane = threadIdx.x & 63;
    int n_tile = n_group * 4 + wave;
    int n = lane & 15;
    int quad = lane >> 4;

    int gate_g = n_tile * 16 + n;
    int dir = gate_g >> 10;
    int gate = gate_g & 1023;
    const __hip_bfloat16* W    = dir ? Wb : Wf;
    const float*          bias = dir ? bbv : bfv;

    int btrow_a = m_tile * 16 + n;
    int word = words[btrow_a];
    const __hip_bfloat16* arow = emb + (size_t)word * DD + quad * 8;
    const __hip_bfloat16* brow = W + (size_t)gate * DD + quad * 8;

    f32x4 acc = {0.f, 0.f, 0.f, 0.f};
#pragma unroll
    for (int kf = 0; kf < 4; ++kf) {
        bf16x8 a = *(const bf16x8*)(arow + kf * 32);
        bf16x8 b = *(const bf16x8*)(brow + kf * 32);
        acc = __builtin_amdgcn_mfma_f32_16x16x32_bf16(a, b, acc, 0, 0, 0);
    }
    float bv = bias[gate];
    size_t dbase = (size_t)dir * (size_t)(BB * TT * G4);
#pragma unroll
    for (int r = 0; r < 4; ++r) {
        int row = m_tile * 16 + quad * 4 + r;
        xg[dbase + (size_t)row * G4 + gate] = __float2bfloat16(acc[r] + bv);
    }
}

// ---------------------------------------------------------------------------
// Kernel 2: LSTM recurrence v3. 128 blocks x 512 threads (8 waves, 2/SIMD).
// Thread j owns gate rows {j, 512+j} (j<256: i,g of cell j; j>=256: f,o of
// cell j-256). Row j: 32 f16-chunks fully in VGPRs. Row 512+j: 8 chunks in
// VGPRs + 7 in LDS + 17 streamed coalesced from the 1 MB L2-resident pack.
// h in f16 LDS (broadcast reads); dots via v_dot2_f32_f16; gates exchanged
// through LDS gbuf; 2 barriers/step.
// ---------------------------------------------------------------------------
__global__ __launch_bounds__(512, 2) void k_lstm(
    const __hip_bfloat16* __restrict__ xg,     // [2][B*T][1024] bf16
    const uint4* __restrict__ Wp,              // f16 packed [2][64][512]
    const int* __restrict__ seq_len,
    __hip_bfloat16* __restrict__ hcat)         // [B*T][512]
{
    int b = blockIdx.x & 63;
    int dir = blockIdx.x >> 6;
    int j = threadIdx.x;   // 0..511

    __shared__ __align__(16) uint4 wB_lds[7 * 512];     // 57344 B (row1 kc 8..14)
    __shared__ float gbuf[2][512];                      //  4096 B
    __shared__ __align__(16) _Float16 hbf[2][HH];       //  1024 B

    const uint4* Wd = Wp + (size_t)dir * 64 * 512;

    uint4 wA[32];
#pragma unroll
    for (int kc = 0; kc < 32; ++kc) wA[kc] = Wd[(kc * 2 + 0) * 512 + j];
    uint4 wB0[8];
#pragma unroll
    for (int kc = 0; kc < 8; ++kc) wB0[kc] = Wd[(kc * 2 + 1) * 512 + j];
#pragma unroll
    for (int kc = 8; kc < 15; ++kc) wB_lds[(kc - 8) * 512 + j] = Wd[(kc * 2 + 1) * 512 + j];

    if (j < HH) hbf[0][j] = (_Float16)0.f;
    float c = 0.f;
    int L = seq_len[b];
    const __hip_bfloat16* xgb = xg + (size_t)dir * (size_t)(BB * TT * G4)
                                   + (size_t)b * TT * G4;

    int tc = dir ? (L - 1) : 0;
    float xv0 = __bfloat162float(xgb[(size_t)tc * G4 + j]);
    float xv1 = __bfloat162float(xgb[(size_t)tc * G4 + 512 + j]);
    __syncthreads();

    for (int t = 0; t < TT; ++t) {
        int cur = t & 1, nxt = cur ^ 1;
        int tn = t + 1;
        int tcn = dir ? ((tn < L) ? (L - 1 - tn) : tn) : tn;
        bool pf = (tn < TT);
        __hip_bfloat16 p0, p1;
        if (pf) {
            p0 = xgb[(size_t)tcn * G4 + j];
            p1 = xgb[(size_t)tcn * G4 + 512 + j];
        }

        // stream group 1: row1 kc 15..23
        uint4 s1[9];
#pragma unroll
        for (int i = 0; i < 9; ++i) s1[i] = Wd[((15 + i) * 2 + 1) * 512 + j];

        const uint4* hv4 = (const uint4*)&hbf[cur][0];   // broadcast
        float a0 = 0.f, a1 = 0.f;
#pragma unroll
        for (int kc = 0; kc < 8; ++kc) {
            uint4 hv = hv4[kc];
            a0 = dot8(a0, wA[kc], hv);
            a1 = dot8(a1, wB0[kc], hv);
        }
#pragma unroll
        for (int kc = 8; kc < 15; ++kc) {
            uint4 hv = hv4[kc];
            a0 = dot8(a0, wA[kc], hv);
            a1 = dot8(a1, wB_lds[(kc - 8) * 512 + j], hv);
        }
        // stream group 2: row1 kc 24..31
        uint4 s2[8];
#pragma unroll
        for (int i = 0; i < 8; ++i) s2[i] = Wd[((24 + i) * 2 + 1) * 512 + j];
#pragma unroll
        for (int kc = 15; kc < 24; ++kc) {
            uint4 hv = hv4[kc];
            a0 = dot8(a0, wA[kc], hv);
            a1 = dot8(a1, s1[kc - 15], hv);
        }
#pragma unroll
        for (int kc = 24; kc < 32; ++kc) {
            uint4 hv = hv4[kc];
            a0 = dot8(a0, wA[kc], hv);
            a1 = dot8(a1, s2[kc - 24], hv);
        }
        gbuf[0][j] = a0 + xv0;
        gbuf[1][j] = a1 + xv1;
        __syncthreads();

        if (j < HH) {
            float gi = gbuf[0][j],      gg = gbuf[1][j];
            float gf = gbuf[0][HH + j], go = gbuf[1][HH + j];
            float i_ = sigf(gi), f_ = sigf(gf), G = tanh_s(gg), o_ = sigf(go);
            c = f_ * c + i_ * G;
            float h = o_ * tanh_s(c);
            hbf[nxt][j] = (_Float16)h;
            hcat[((size_t)(b * TT + tc)) * (2 * HH) + dir * HH + j] = __float2bfloat16(h);
        }
        if (pf) { xv0 = __bfloat162float(p0); xv1 = __bfloat162float(p1); }
        tc = tcn;
        __syncthreads();
    }
}

// ---------------------------------------------------------------------------
// Kernel 3: feats = hcat @ fc_W^T + fc_b ; logits = log_softmax(feats)
// ---------------------------------------------------------------------------
__global__ __launch_bounds__(64) void k_fc(
    const __hip_bfloat16* __restrict__ hcat,
    const __hip_bfloat16* __restrict__ fcW,
    const float* __restrict__ fcb,
    float* __restrict__ logits)
{
    int row = blockIdx.x;
    int tid = threadIdx.x;
    __shared__ __align__(16) float hrow[2 * HH];
    __shared__ float fbuf[CC + 2];

    {
        uint4 v = *(const uint4*)(hcat + (size_t)row * (2 * HH) + tid * 8);
        float* d = &hrow[tid * 8];
        d[0] = bl16(v.x); d[1] = bh16(v.x);
        d[2] = bl16(v.y); d[3] = bh16(v.y);
        d[4] = bl16(v.z); d[5] = bh16(v.z);
        d[6] = bl16(v.w); d[7] = bh16(v.w);
    }
    __syncthreads();

    if (tid < CC) {
        float acc = fcb[tid];
        const uint4* wr = (const uint4*)(fcW + (size_t)tid * (2 * HH));
#pragma unroll 8
        for (int kc = 0; kc < 64; ++kc) {
            uint4 wv = wr[kc];
            float4 h0 = *(const float4*)&hrow[kc * 8];
            float4 h1 = *(const float4*)&hrow[kc * 8 + 4];
            acc = fmaf(bl16(wv.x), h0.x, acc); acc = fmaf(bh16(wv.x), h0.y, acc);
            acc = fmaf(bl16(wv.y), h0.z, acc); acc = fmaf(bh16(wv.y), h0.w, acc);
            acc = fmaf(bl16(wv.z), h1.x, acc); acc = fmaf(bh16(wv.z), h1.y, acc);
            acc = fmaf(bl16(wv.w), h1.z, acc); acc = fmaf(bh16(wv.w), h1.w, acc);
        }
        fbuf[tid] = acc;
    }
    __syncthreads();

    float m = -1e30f;
    for (int i = 0; i < CC; ++i) m = fmaxf(m, fbuf[i]);
    float s = 0.f;
    for (int i = 0; i < CC; ++i) s += __expf(fbuf[i] - m);
    float lns = __logf(s);
    if (tid < CC) logits[(size_t)row * CC + tid] = fbuf[tid] - m - lns;
}

// ---------------------------------------------------------------------------
// Kernel 4: CRF forward scan + gold score; per-batch loss -> loss_b[b]
// ---------------------------------------------------------------------------
__global__ __launch_bounds__(256) void k_crf(
    const float* __restrict__ logits,
    const int* __restrict__ target,
    const int* __restrict__ seq_len,
    const float* __restrict__ trans,
    const float* __restrict__ start_s,
    const float* __restrict__ end_s,
    float* __restrict__ loss_b)
{
    const float L2E = 1.4426950408889634f;
    const float LN2 = 0.6931471805599453f;
    int b = blockIdx.x;
    int tid = threadIdx.x;
    int q = tid >> 6;
    int j = tid & 63;
    bool act = (j < CC);
    int L = seq_len[b];
    const float* lg = logits + (size_t)b * TT * CC;

    __shared__ float alpha2[64];
    __shared__ float mpart[4][64];
    __shared__ float spart[4][64];
    __shared__ float red[256];
    __shared__ float nbuf[CC + 2];

    int i0 = q * 13;
    int icnt = min(13, CC - i0);
    float treg[13];
    if (act) {
#pragma unroll
        for (int s = 0; s < 13; ++s)
            if (s < icnt) treg[s] = L2E * trans[(i0 + s) * CC + j];
    }
    if (q == 0 && act) alpha2[j] = L2E * (lg[j] + start_s[j]);
    __syncthreads();

    float v[13];
    for (int t = 1; t < L; ++t) {
        float mq = -1e30f;
        if (act) {
#pragma unroll
            for (int s = 0; s < 13; ++s)
                if (s < icnt) { v[s] = alpha2[i0 + s] + treg[s]; mq = fmaxf(mq, v[s]); }
        }
        mpart[q][j] = mq;
        __syncthreads();
        float M = fmaxf(fmaxf(mpart[0][j], mpart[1][j]), fmaxf(mpart[2][j], mpart[3][j]));
        float sq = 0.f;
        if (act) {
#pragma unroll
            for (int s = 0; s < 13; ++s)
                if (s < icnt) sq += exp2f(v[s] - M);
        }
        spart[q][j] = sq;
        __syncthreads();
        if (q == 0 && act) {
            float S = spart[0][j] + spart[1][j] + spart[2][j] + spart[3][j];
            alpha2[j] = M + log2f(S) + L2E * lg[(size_t)t * CC + j];
        }
        __syncthreads();
    }

    if (q == 0 && act) nbuf[j] = alpha2[j] + L2E * end_s[j];

    float gp = 0.f;
    const int* tg = target + b * TT;
    for (int t = tid; t < TT; t += 256) {
        if (t < L) {
            int c = tg[t];
            gp += lg[(size_t)t * CC + c];
            if (t >= 1) gp += trans[tg[t - 1] * CC + c];
        }
    }
    red[tid] = gp;
    __syncthreads();

    if (tid == 0) {
        float m2 = -1e30f;
        for (int i = 0; i < CC; ++i) m2 = fmaxf(m2, nbuf[i]);
        float s2 = 0.f;
        for (int i = 0; i < CC; ++i) s2 += exp2f(nbuf[i] - m2);
        float norm_nat = (m2 + log2f(s2)) * LN2;
        float g = 0.f;
        for (int i = 0; i < 256; ++i) g += red[i];
        g += start_s[tg[0]] + end_s[tg[L - 1]];
        loss_b[b] = norm_nat - g;
    }
}

// Parallel final reduction (one wave)
__global__ void k_fin(const float* __restrict__ loss_b, float* __restrict__ out)
{
    int t = threadIdx.x;
    float v = loss_b[t];
#pragma unroll
    for (int o = 32; o > 0; o >>= 1) v += __shfl_down(v, o);
    if (t == 0) out[0] = v * (1.f / BB);
}

// ---------------------------------------------------------------------------
extern "C" void kernel_launch(void* const* d_in, const int* in_sizes, int n_in,
                              void* d_out, int out_size, void* d_ws, size_t ws_size,
                              hipStream_t stream)
{
    const int* words   = (const int*)d_in[0];
    const int* target  = (const int*)d_in[1];
    const int* seq_len = (const int*)d_in[2];
    const float* emb    = (const float*)d_in[3];
    const float* W_ih_f = (const float*)d_in[4];
    const float* W_hh_f = (const float*)d_in[5];
    const float* b_f    = (const float*)d_in[6];
    const float* W_ih_b = (const float*)d_in[7];
    const float* W_hh_b = (const float*)d_in[8];
    const float* b_b    = (const float*)d_in[9];
    const float* fc_W   = (const float*)d_in[10];
    const float* fc_b   = (const float*)d_in[11];
    const float* trans  = (const float*)d_in[12];
    const float* start_s= (const float*)d_in[13];
    const float* end_s  = (const float*)d_in[14];

    char* ws = (char*)d_ws;
    // workspace layout (bytes):
    //   xg     : 134217728                         @ 0
    //   hcat   :  33554432                         @ 134217728
    //   logits :   6553600                         @ 167772160
    //     (Wp f16 pack, 1 MB, overlaps logits: consumed by k_lstm BEFORE
    //      k_fc writes logits)
    //   loss_b :       256                         @ 174325760
    //   emb_bf :  12800000                         @ 174326016
    //   wih_f  :    262144                         @ 187126016
    //   wih_b  :    262144                         @ 187912448
    //   fcw_bf :     51200                         @ 188698880
    __hip_bfloat16* xg     = (__hip_bfloat16*)ws;
    __hip_bfloat16* hcat   = (__hip_bfloat16*)(ws + 134217728);
    float*          logits = (float*)(ws + 167772160);
    uint4*          Wp     = (uint4*)(ws + 167772160);
    float*          loss_b = (float*)(ws + 174325760);
    __hip_bfloat16* emb_bf = (__hip_bfloat16*)(ws + 174326016);
    __hip_bfloat16* wih_f  = (__hip_bfloat16*)(ws + 187126016);
    __hip_bfloat16* wih_b  = (__hip_bfloat16*)(ws + 187912448);
    __hip_bfloat16* fcw_bf = (__hip_bfloat16*)(ws + 188698880);

    k_cvt<<<3125, 256, 0, stream>>>(emb,    emb_bf, 6400000);
    k_cvt<<<64,   256, 0, stream>>>(W_ih_f, wih_f,  131072);
    k_cvt<<<64,   256, 0, stream>>>(W_ih_b, wih_b,  131072);
    k_cvt<<<13,   256, 0, stream>>>(fc_W,   fcw_bf, 25600);
    k_pack<<<128, 512, 0, stream>>>(W_hh_f, W_hh_b, Wp);

    k_xg  <<<65536, 256, 0, stream>>>(words, emb_bf, wih_f, b_f, wih_b, b_b, xg);
    k_lstm<<<128, 512, 0, stream>>>(xg, Wp, seq_len, hcat);
    k_fc  <<<32768, 64, 0, stream>>>(hcat, fcw_bf, fc_b, logits);
    k_crf <<<64, 256, 0, stream>>>(logits, target, seq_len, trans, start_s, end_s, loss_b);
    k_fin <<<1, 64, 0, stream>>>(loss_b, (float*)d_out);
}

// Round 8
// 1891.974 us; speedup vs baseline: 4.5507x; 1.0953x over previous
//
#include <hip/hip_runtime.h>
#include <hip/hip_bf16.h>

// Problem constants
#define BB 64
#define TT 512
#define DD 128
#define HH 256
#define G4 1024   // 4*H
#define CC 50

typedef __bf16 bf16x8 __attribute__((ext_vector_type(8)));
typedef float  f32x4  __attribute__((ext_vector_type(4)));
typedef _Float16 h16x2 __attribute__((ext_vector_type(2)));

#if defined(__has_builtin)
#if __has_builtin(__builtin_amdgcn_fdot2)
#define HAS_FDOT2 1
#endif
#endif

__device__ __forceinline__ float bl16(unsigned u) { return __uint_as_float(u << 16); }
__device__ __forceinline__ float bh16(unsigned u) { return __uint_as_float(u & 0xffff0000u); }

__device__ __forceinline__ float sigf(float x) {
    return 1.f / (1.f + __expf(-x));
}
__device__ __forceinline__ float tanh_s(float x) {
    float ax = fabsf(x);
    float e = __expf(-2.f * ax);
    float r = (1.f - e) / (1.f + e);
    return copysignf(r, x);
}

// 8-element f16 dot product chunk, f32 accumulate
__device__ __forceinline__ float dot8(float acc, uint4 w, uint4 h) {
#ifdef HAS_FDOT2
    acc = __builtin_amdgcn_fdot2(__builtin_bit_cast(h16x2, w.x),
                                 __builtin_bit_cast(h16x2, h.x), acc, false);
    acc = __builtin_amdgcn_fdot2(__builtin_bit_cast(h16x2, w.y),
                                 __builtin_bit_cast(h16x2, h.y), acc, false);
    acc = __builtin_amdgcn_fdot2(__builtin_bit_cast(h16x2, w.z),
                                 __builtin_bit_cast(h16x2, h.z), acc, false);
    acc = __builtin_amdgcn_fdot2(__builtin_bit_cast(h16x2, w.w),
                                 __builtin_bit_cast(h16x2, h.w), acc, false);
#else
    {
        h16x2 a = __builtin_bit_cast(h16x2, w.x), b = __builtin_bit_cast(h16x2, h.x);
        acc = fmaf((float)a.x, (float)b.x, acc); acc = fmaf((float)a.y, (float)b.y, acc);
        a = __builtin_bit_cast(h16x2, w.y); b = __builtin_bit_cast(h16x2, h.y);
        acc = fmaf((float)a.x, (float)b.x, acc); acc = fmaf((float)a.y, (float)b.y, acc);
        a = __builtin_bit_cast(h16x2, w.z); b = __builtin_bit_cast(h16x2, h.z);
        acc = fmaf((float)a.x, (float)b.x, acc); acc = fmaf((float)a.y, (float)b.y, acc);
        a = __builtin_bit_cast(h16x2, w.w); b = __builtin_bit_cast(h16x2, h.w);
        acc = fmaf((float)a.x, (float)b.x, acc); acc = fmaf((float)a.y, (float)b.y, acc);
    }
#endif
    return acc;
}

// ---------------------------------------------------------------------------
// Kernel 0: f32 -> bf16 conversion (8 elements/thread)
// ---------------------------------------------------------------------------
__global__ __launch_bounds__(256) void k_cvt(
    const float* __restrict__ src, __hip_bfloat16* __restrict__ dst, int n)
{
    int i = (blockIdx.x * 256 + threadIdx.x) * 8;
    if (i + 8 <= n) {
        float4 a = *(const float4*)(src + i);
        float4 b = *(const float4*)(src + i + 4);
        __hip_bfloat16 o[8];
        o[0] = __float2bfloat16(a.x); o[1] = __float2bfloat16(a.y);
        o[2] = __float2bfloat16(a.z); o[3] = __float2bfloat16(a.w);
        o[4] = __float2bfloat16(b.x); o[5] = __float2bfloat16(b.y);
        o[6] = __float2bfloat16(b.z); o[7] = __float2bfloat16(b.w);
        *(uint4*)(dst + i) = *(const uint4*)o;
    }
}

// ---------------------------------------------------------------------------
// Kernel 0b: pack W_hh (f32 [1024][256]) -> f16 lane-coalesced chunks.
// k_lstm thread j (of 512) owns rows {j, 512+j}.
// Wp[dir*64 + kc*2 + half][j] = 8 f16 of row (half*512 + j), k in [8kc, 8kc+8)
// ---------------------------------------------------------------------------
__global__ __launch_bounds__(512) void k_pack(
    const float* __restrict__ Wf, const float* __restrict__ Wb,
    uint4* __restrict__ Wp)
{
    int blk = blockIdx.x;
    int half = blk & 1;
    int kc = (blk >> 1) & 31;
    int dir = blk >> 6;
    int j = threadIdx.x;
    int row = half * 512 + j;
    const float* src = (dir ? Wb : Wf) + (size_t)row * 256 + kc * 8;
    float4 a = *(const float4*)src;
    float4 b = *(const float4*)(src + 4);
    _Float16 o[8];
    o[0] = (_Float16)a.x; o[1] = (_Float16)a.y;
    o[2] = (_Float16)a.z; o[3] = (_Float16)a.w;
    o[4] = (_Float16)b.x; o[5] = (_Float16)b.y;
    o[6] = (_Float16)b.z; o[7] = (_Float16)b.w;
    Wp[((size_t)dir * 64 + kc * 2 + half) * 512 + j] = *(const uint4*)o;
}

// ---------------------------------------------------------------------------
// Kernel 1 (v2): xg = emb[words] @ W_ih^T + b, LDS-staged GEMM.
// 512 blocks x 256 threads. Block owns 64 bt-rows x ALL 2048 gates.
// emb read directly as f32 (staged once -> bf16 LDS); A-frags in registers;
// W_ih (bf16, 512 KB, L2-resident) streamed; 512 MFMA/wave.
// ---------------------------------------------------------------------------
__global__ __launch_bounds__(256, 2) void k_xg(
    const int* __restrict__ words,
    const float* __restrict__ embf,           // f32 [50000][128]
    const __hip_bfloat16* __restrict__ Wih,   // bf16 [2048][128] (fwd|bwd)
    const float* __restrict__ bfv, const float* __restrict__ bbv,
    __hip_bfloat16* __restrict__ xg)
{
    __shared__ __align__(16) __hip_bfloat16 A[64][136];   // pad->272B row, 16B-aligned
    int tid = threadIdx.x;
    int bt0 = blockIdx.x * 64;

    // stage 64 emb rows (f32 -> bf16): 4 threads/row, 32 elems each
    {
        int r = tid >> 2;
        int c0 = (tid & 3) * 32;
        int word = words[bt0 + r];
        const float* src = embf + (size_t)word * DD + c0;
#pragma unroll
        for (int i = 0; i < 8; ++i) {
            float4 v = *(const float4*)(src + i * 4);
            __hip_bfloat16 o[4] = {__float2bfloat16(v.x), __float2bfloat16(v.y),
                                   __float2bfloat16(v.z), __float2bfloat16(v.w)};
            *(uint2*)&A[r][c0 + i * 4] = *(const uint2*)o;
        }
    }
    __syncthreads();

    int wave = tid >> 6, lane = tid & 63;
    int m = lane & 15, quad = lane >> 4;

    // A fragments: 16 (m_sub, kf) combos held in registers (64 VGPRs)
    bf16x8 afr[4][4];
#pragma unroll
    for (int ms = 0; ms < 4; ++ms)
#pragma unroll
        for (int kf = 0; kf < 4; ++kf)
            afr[ms][kf] = *(const bf16x8*)&A[ms * 16 + m][quad * 8 + kf * 32];

    // each wave: 32 n_tiles of 16 gates
#pragma unroll 1
    for (int i = 0; i < 32; ++i) {
        int nt = wave * 32 + i;
        int gate_g = nt * 16 + m;            // 0..2047
        int dir = gate_g >> 10;
        int gate = gate_g & 1023;
        const __hip_bfloat16* brow = Wih + (size_t)gate_g * DD + quad * 8;
        bf16x8 bfr[4];
#pragma unroll
        for (int kf = 0; kf < 4; ++kf) bfr[kf] = *(const bf16x8*)(brow + kf * 32);
        float bv = dir ? bbv[gate] : bfv[gate];
        size_t dbase = (size_t)dir * (size_t)(BB * TT * G4);

#pragma unroll
        for (int ms = 0; ms < 4; ++ms) {
            f32x4 acc = {0.f, 0.f, 0.f, 0.f};
#pragma unroll
            for (int kf = 0; kf < 4; ++kf)
                acc = __builtin_amdgcn_mfma_f32_16x16x32_bf16(afr[ms][kf], bfr[kf], acc, 0, 0, 0);
#pragma unroll
            for (int r = 0; r < 4; ++r) {
                int btrow = bt0 + ms * 16 + quad * 4 + r;
                xg[dbase + (size_t)btrow * G4 + gate] = __float2bfloat16(acc[r] + bv);
            }
        }
    }
}

// ---------------------------------------------------------------------------
// Kernel 2: LSTM recurrence v4 = v3 + amdgpu_waves_per_eu(2,2) so the
// allocator actually keeps the 40 weight chunks (160 VGPRs) resident.
// 128 blocks x 512 threads (8 waves, pinned 2/SIMD).
// ---------------------------------------------------------------------------
__global__ __launch_bounds__(512)
__attribute__((amdgpu_waves_per_eu(2, 2)))
void k_lstm(
    const __hip_bfloat16* __restrict__ xg,     // [2][B*T][1024] bf16
    const uint4* __restrict__ Wp,              // f16 packed [2][64][512]
    const int* __restrict__ seq_len,
    __hip_bfloat16* __restrict__ hcat)         // [B*T][512]
{
    int b = blockIdx.x & 63;
    int dir = blockIdx.x >> 6;
    int j = threadIdx.x;   // 0..511

    __shared__ __align__(16) uint4 wB_lds[7 * 512];     // 57344 B (row1 kc 8..14)
    __shared__ float gbuf[2][512];                      //  4096 B
    __shared__ __align__(16) _Float16 hbf[2][HH];       //  1024 B

    const uint4* Wd = Wp + (size_t)dir * 64 * 512;

    uint4 wA[32];
#pragma unroll
    for (int kc = 0; kc < 32; ++kc) wA[kc] = Wd[(kc * 2 + 0) * 512 + j];
    uint4 wB0[8];
#pragma unroll
    for (int kc = 0; kc < 8; ++kc) wB0[kc] = Wd[(kc * 2 + 1) * 512 + j];
#pragma unroll
    for (int kc = 8; kc < 15; ++kc) wB_lds[(kc - 8) * 512 + j] = Wd[(kc * 2 + 1) * 512 + j];

    if (j < HH) hbf[0][j] = (_Float16)0.f;
    float c = 0.f;
    int L = seq_len[b];
    const __hip_bfloat16* xgb = xg + (size_t)dir * (size_t)(BB * TT * G4)
                                   + (size_t)b * TT * G4;

    int tc = dir ? (L - 1) : 0;
    float xv0 = __bfloat162float(xgb[(size_t)tc * G4 + j]);
    float xv1 = __bfloat162float(xgb[(size_t)tc * G4 + 512 + j]);
    __syncthreads();

    for (int t = 0; t < TT; ++t) {
        int cur = t & 1, nxt = cur ^ 1;
        int tn = t + 1;
        int tcn = dir ? ((tn < L) ? (L - 1 - tn) : tn) : tn;
        bool pf = (tn < TT);
        __hip_bfloat16 p0, p1;
        if (pf) {
            p0 = xgb[(size_t)tcn * G4 + j];
            p1 = xgb[(size_t)tcn * G4 + 512 + j];
        }

        // stream group 1: row1 kc 15..23
        uint4 s1[9];
#pragma unroll
        for (int i = 0; i < 9; ++i) s1[i] = Wd[((15 + i) * 2 + 1) * 512 + j];

        const uint4* hv4 = (const uint4*)&hbf[cur][0];   // broadcast
        float a0 = 0.f, a1 = 0.f;
#pragma unroll
        for (int kc = 0; kc < 8; ++kc) {
            uint4 hv = hv4[kc];
            a0 = dot8(a0, wA[kc], hv);
            a1 = dot8(a1, wB0[kc], hv);
        }
#pragma unroll
        for (int kc = 8; kc < 15; ++kc) {
            uint4 hv = hv4[kc];
            a0 = dot8(a0, wA[kc], hv);
            a1 = dot8(a1, wB_lds[(kc - 8) * 512 + j], hv);
        }
        // stream group 2: row1 kc 24..31
        uint4 s2[8];
#pragma unroll
        for (int i = 0; i < 8; ++i) s2[i] = Wd[((24 + i) * 2 + 1) * 512 + j];
#pragma unroll
        for (int kc = 15; kc < 24; ++kc) {
            uint4 hv = hv4[kc];
            a0 = dot8(a0, wA[kc], hv);
            a1 = dot8(a1, s1[kc - 15], hv);
        }
#pragma unroll
        for (int kc = 24; kc < 32; ++kc) {
            uint4 hv = hv4[kc];
            a0 = dot8(a0, wA[kc], hv);
            a1 = dot8(a1, s2[kc - 24], hv);
        }
        gbuf[0][j] = a0 + xv0;
        gbuf[1][j] = a1 + xv1;
        __syncthreads();

        if (j < HH) {
            float gi = gbuf[0][j],      gg = gbuf[1][j];
            float gf = gbuf[0][HH + j], go = gbuf[1][HH + j];
            float i_ = sigf(gi), f_ = sigf(gf), G = tanh_s(gg), o_ = sigf(go);
            c = f_ * c + i_ * G;
            float h = o_ * tanh_s(c);
            hbf[nxt][j] = (_Float16)h;
            hcat[((size_t)(b * TT + tc)) * (2 * HH) + dir * HH + j] = __float2bfloat16(h);
        }
        if (pf) { xv0 = __bfloat162float(p0); xv1 = __bfloat162float(p1); }
        tc = tcn;
        __syncthreads();
    }
}

// ---------------------------------------------------------------------------
// Kernel 3: feats = hcat @ fc_W^T + fc_b ; logits = log_softmax(feats)
// ---------------------------------------------------------------------------
__global__ __launch_bounds__(64) void k_fc(
    const __hip_bfloat16* __restrict__ hcat,
    const __hip_bfloat16* __restrict__ fcW,
    const float* __restrict__ fcb,
    float* __restrict__ logits)
{
    int row = blockIdx.x;
    int tid = threadIdx.x;
    __shared__ __align__(16) float hrow[2 * HH];
    __shared__ float fbuf[CC + 2];

    {
        uint4 v = *(const uint4*)(hcat + (size_t)row * (2 * HH) + tid * 8);
        float* d = &hrow[tid * 8];
        d[0] = bl16(v.x); d[1] = bh16(v.x);
        d[2] = bl16(v.y); d[3] = bh16(v.y);
        d[4] = bl16(v.z); d[5] = bh16(v.z);
        d[6] = bl16(v.w); d[7] = bh16(v.w);
    }
    __syncthreads();

    if (tid < CC) {
        float acc = fcb[tid];
        const uint4* wr = (const uint4*)(fcW + (size_t)tid * (2 * HH));
#pragma unroll 8
        for (int kc = 0; kc < 64; ++kc) {
            uint4 wv = wr[kc];
            float4 h0 = *(const float4*)&hrow[kc * 8];
            float4 h1 = *(const float4*)&hrow[kc * 8 + 4];
            acc = fmaf(bl16(wv.x), h0.x, acc); acc = fmaf(bh16(wv.x), h0.y, acc);
            acc = fmaf(bl16(wv.y), h0.z, acc); acc = fmaf(bh16(wv.y), h0.w, acc);
            acc = fmaf(bl16(wv.z), h1.x, acc); acc = fmaf(bh16(wv.z), h1.y, acc);
            acc = fmaf(bl16(wv.w), h1.z, acc); acc = fmaf(bh16(wv.w), h1.w, acc);
        }
        fbuf[tid] = acc;
    }
    __syncthreads();

    float m = -1e30f;
    for (int i = 0; i < CC; ++i) m = fmaxf(m, fbuf[i]);
    float s = 0.f;
    for (int i = 0; i < CC; ++i) s += __expf(fbuf[i] - m);
    float lns = __logf(s);
    if (tid < CC) logits[(size_t)row * CC + tid] = fbuf[tid] - m - lns;
}

// ---------------------------------------------------------------------------
// Kernel 4: CRF forward scan + gold score; per-batch loss -> loss_b[b]
// ---------------------------------------------------------------------------
__global__ __launch_bounds__(256) void k_crf(
    const float* __restrict__ logits,
    const int* __restrict__ target,
    const int* __restrict__ seq_len,
    const float* __restrict__ trans,
    const float* __restrict__ start_s,
    const float* __restrict__ end_s,
    float* __restrict__ loss_b)
{
    const float L2E = 1.4426950408889634f;
    const float LN2 = 0.6931471805599453f;
    int b = blockIdx.x;
    int tid = threadIdx.x;
    int q = tid >> 6;
    int j = tid & 63;
    bool act = (j < CC);
    int L = seq_len[b];
    const float* lg = logits + (size_t)b * TT * CC;

    __shared__ float alpha2[64];
    __shared__ float mpart[4][64];
    __shared__ float spart[4][64];
    __shared__ float red[256];
    __shared__ float nbuf[CC + 2];

    int i0 = q * 13;
    int icnt = min(13, CC - i0);
    float treg[13];
    if (act) {
#pragma unroll
        for (int s = 0; s < 13; ++s)
            if (s < icnt) treg[s] = L2E * trans[(i0 + s) * CC + j];
    }
    if (q == 0 && act) alpha2[j] = L2E * (lg[j] + start_s[j]);
    __syncthreads();

    float v[13];
    for (int t = 1; t < L; ++t) {
        float mq = -1e30f;
        if (act) {
#pragma unroll
            for (int s = 0; s < 13; ++s)
                if (s < icnt) { v[s] = alpha2[i0 + s] + treg[s]; mq = fmaxf(mq, v[s]); }
        }
        mpart[q][j] = mq;
        __syncthreads();
        float M = fmaxf(fmaxf(mpart[0][j], mpart[1][j]), fmaxf(mpart[2][j], mpart[3][j]));
        float sq = 0.f;
        if (act) {
#pragma unroll
            for (int s = 0; s < 13; ++s)
                if (s < icnt) sq += exp2f(v[s] - M);
        }
        spart[q][j] = sq;
        __syncthreads();
        if (q == 0 && act) {
            float S = spart[0][j] + spart[1][j] + spart[2][j] + spart[3][j];
            alpha2[j] = M + log2f(S) + L2E * lg[(size_t)t * CC + j];
        }
        __syncthreads();
    }

    if (q == 0 && act) nbuf[j] = alpha2[j] + L2E * end_s[j];

    float gp = 0.f;
    const int* tg = target + b * TT;
    for (int t = tid; t < TT; t += 256) {
        if (t < L) {
            int c = tg[t];
            gp += lg[(size_t)t * CC + c];
            if (t >= 1) gp += trans[tg[t - 1] * CC + c];
        }
    }
    red[tid] = gp;
    __syncthreads();

    if (tid == 0) {
        float m2 = -1e30f;
        for (int i = 0; i < CC; ++i) m2 = fmaxf(m2, nbuf[i]);
        float s2 = 0.f;
        for (int i = 0; i < CC; ++i) s2 += exp2f(nbuf[i] - m2);
        float norm_nat = (m2 + log2f(s2)) * LN2;
        float g = 0.f;
        for (int i = 0; i < 256; ++i) g += red[i];
        g += start_s[tg[0]] + end_s[tg[L - 1]];
        loss_b[b] = norm_nat - g;
    }
}

// Parallel final reduction (one wave)
__global__ void k_fin(const float* __restrict__ loss_b, float* __restrict__ out)
{
    int t = threadIdx.x;
    float v = loss_b[t];
#pragma unroll
    for (int o = 32; o > 0; o >>= 1) v += __shfl_down(v, o);
    if (t == 0) out[0] = v * (1.f / BB);
}

// ---------------------------------------------------------------------------
extern "C" void kernel_launch(void* const* d_in, const int* in_sizes, int n_in,
                              void* d_out, int out_size, void* d_ws, size_t ws_size,
                              hipStream_t stream)
{
    const int* words   = (const int*)d_in[0];
    const int* target  = (const int*)d_in[1];
    const int* seq_len = (const int*)d_in[2];
    const float* emb    = (const float*)d_in[3];
    const float* W_ih_f = (const float*)d_in[4];
    const float* W_hh_f = (const float*)d_in[5];
    const float* b_f    = (const float*)d_in[6];
    const float* W_ih_b = (const float*)d_in[7];
    const float* W_hh_b = (const float*)d_in[8];
    const float* b_b    = (const float*)d_in[9];
    const float* fc_W   = (const float*)d_in[10];
    const float* fc_b   = (const float*)d_in[11];
    const float* trans  = (const float*)d_in[12];
    const float* start_s= (const float*)d_in[13];
    const float* end_s  = (const float*)d_in[14];

    char* ws = (char*)d_ws;
    // workspace layout (bytes):
    //   xg     : 134217728                         @ 0
    //   hcat   :  33554432                         @ 134217728
    //   logits :   6553600                         @ 167772160
    //     (Wp f16 lstm pack, 1 MB, overlaps logits: consumed by k_lstm
    //      BEFORE k_fc writes logits)
    //   loss_b :       256                         @ 174325760
    //   wihall :    524288  (bf16 [2048][128])     @ 174326016
    //   fcw_bf :     51200                         @ 174850304
    __hip_bfloat16* xg     = (__hip_bfloat16*)ws;
    __hip_bfloat16* hcat   = (__hip_bfloat16*)(ws + 134217728);
    float*          logits = (float*)(ws + 167772160);
    uint4*          Wp     = (uint4*)(ws + 167772160);
    float*          loss_b = (float*)(ws + 174325760);
    __hip_bfloat16* wihall = (__hip_bfloat16*)(ws + 174326016);
    __hip_bfloat16* fcw_bf = (__hip_bfloat16*)(ws + 174850304);

    k_cvt<<<64,  256, 0, stream>>>(W_ih_f, wihall,          131072);
    k_cvt<<<64,  256, 0, stream>>>(W_ih_b, wihall + 131072, 131072);
    k_cvt<<<13,  256, 0, stream>>>(fc_W,   fcw_bf,          25600);
    k_pack<<<128, 512, 0, stream>>>(W_hh_f, W_hh_b, Wp);

    k_xg  <<<512, 256, 0, stream>>>(words, emb, wihall, b_f, b_b, xg);
    k_lstm<<<128, 512, 0, stream>>>(xg, Wp, seq_len, hcat);
    k_fc  <<<32768, 64, 0, stream>>>(hcat, fcw_bf, fc_b, logits);
    k_crf <<<64, 256, 0, stream>>>(logits, target, seq_len, trans, start_s, end_s, loss_b);
    k_fin <<<1, 64, 0, stream>>>(loss_b, (float*)d_out);
}